// Round 5
// baseline (155.696 us; speedup 1.0000x reference)
//
#include <hip/hip_runtime.h>

typedef __attribute__((ext_vector_type(8))) short bf16x8;
typedef __attribute__((ext_vector_type(4))) float f32x4;

#define AS1 __attribute__((address_space(1)))
#define AS3 __attribute__((address_space(3)))

__device__ static inline void gl2lds16(const void* g, void* l) {
  // async global->LDS, 16B per lane; HW writes wave-uniform base + lane*16
  __builtin_amdgcn_global_load_lds((const AS1 unsigned int*)g, (AS3 unsigned int*)l, 16, 0, 0);
}

__device__ static inline unsigned short f2bf(float x) {
  unsigned int u = __float_as_uint(x);
  unsigned int r = u + 0x7FFFu + ((u >> 16) & 1u);  // round-to-nearest-even
  return (unsigned short)(r >> 16);
}

// Prep (A-cast stays fused into the GEMM):
//  bx < 1024   : code_book row cast -> b[1024][1024] bf16 + rowsum[1024]
//  bx >= 1024  : labels normalize (int64-vs-int32 autodetect); bx==1024,t==0 zeroes lin/out
__global__ __launch_bounds__(256) void prep_bl_k(
    const float* __restrict__ cb, const int* __restrict__ labraw,
    unsigned short* __restrict__ b, float* __restrict__ rowsum,
    int* __restrict__ labs, float* __restrict__ lin, float* __restrict__ out) {
  const int bx = blockIdx.x, t = threadIdx.x;
  if (bx < 1024) {
    int n = bx;
    float s = 0.f;
#pragma unroll
    for (int j = 0; j < 4; ++j) {
      int c = t + j * 256;
      float v = 0.f;
      if (n < 1000 && c < 1000) v = cb[(size_t)n * 1000 + c];
      s += v;
      b[((size_t)n << 10) + c] = f2bf(v);
    }
    __shared__ float red[256];
    red[t] = s;
    __syncthreads();
    for (int o = 128; o > 0; o >>= 1) {
      if (t < o) red[t] += red[t + o];
      __syncthreads();
    }
    if (t == 0) rowsum[n] = (n < 1000) ? red[0] : 0.f;
  } else {
    __shared__ int nz;
    if (t == 0) nz = 0;
    __syncthreads();
    if (labraw[2 * t + 1] != 0) atomicAdd(&nz, 1);
    __syncthreads();
    bool is64 = (nz < 32);
    int row = (bx - 1024) * 256 + t;
    labs[row] = is64 ? labraw[2 * row] : labraw[row];
    if (bx == 1024 && t == 0) { lin[0] = 0.f; out[0] = 0.f; }
  }
}

// R13: TLP fix. R12 post-mortem: FETCH 134->41 MB (swizzle worked) but BW
// 0.56 TB/s + MfmaUtil 17% + VALUBusy 19% = latency-serialized. Root cause:
// 1 block/CU -> every s_barrier idles the whole CU behind the slowest wave's
// load; counted vmcnt can't help when there is no other block to issue.
// Changes:
//  * 512 blocks x 256 threads (4 waves 2x2), block tile 256x128, wave tile
//    128x64 unchanged -> 2 blocks/CU (reg budget acc128+~120 = 248 <= 256,
//    LDS 56 KB x2 = 112 <= 160). Independent blocks overlap across barriers
//    (m114 mechanism) - the latency hiding R12 lacked.
//  * B: 3-buffer (8 KB each). Region J issues B(J+2)->b_st, drains it at end
//    of region J+1 via vmcnt(10) -> a full region of slack (R12 waited B in
//    its own region). A: 2-buffer LDS + single 8xfloat4 reg set.
//  * FIFO ledger, steady outstanding 10 = A(J+1)x8 + B(J+1)x2. Region J:
//    COMPUTE(J); CVWRA(J+1) (compiler waits vmcnt<=2, B stays in flight);
//    LOADA(J+2); gl_lds B(J+2); vmcnt(10) lgkm(0) (drains B(J+1)+ds_writes);
//    barrier. Tail: J=30 CVWRA(31)+vmcnt(0); J=31 compute only.
//  * XCD swizzle extended: 512 = 8 XCD-chunks x 64; each XCD owns 8rt x 8ct
//    -> A panel read once from HBM, B (2 MB) L3-shared. Bijective.
// R7 LDS swizzle law kept everywhere: LDS chunk (row, slot) holds global
// k-chunk slot ^ ((row>>1)&3); fragment read offset ar*32+((g16^((ar>>1)&3))<<3).
// Tile-31 A cols 992..999 valid only for sg==0, predicated (no OOB).
__global__ __launch_bounds__(256, 2) void coding_loss_k(
    const float* __restrict__ In,           // [16384][1000] f32 raw inputs
    const unsigned short* __restrict__ Bg,  // [1024][1024] bf16 = code
    const float* __restrict__ rowsum,       // [1024]
    const int* __restrict__ labels,         // [16384] int32 (normalized)
    float* __restrict__ Z,                  // [8][16384] partial expsums
    float* __restrict__ lin) {              // scalar (zeroed by prep)
  __shared__ __align__(16) unsigned short lds[28672];  // 56 KB
  // A bufs: lds + {0, 8192}; B bufs: lds + 16384 + q*4096, q = 0..2

  const int t    = threadIdx.x;
  const int lane = t & 63;
  const int w    = t >> 6;   // 0..3
  const int wr   = w >> 1;   // 0..1: rows wr*128..+128
  const int wc   = w & 1;    // 0..1: cols wc*64..+64
  const int g16  = lane >> 4;
  const int c16  = lane & 15;
  // XCD-chunked bijective swizzle (8 XCDs x 64 blocks): each XCD 8rt x 8ct
  const int bid  = blockIdx.x;
  const int L    = ((bid & 7) << 6) | (bid >> 3);
  const int ct   = L & 7;    // 0..7: cols ct*128
  const int rt   = L >> 3;   // 0..63: rows rt*256
  const int r0   = rt << 8;
  const int c0   = ct << 7;

  // ---- staging maps ----
  // A: 256 rows x 32 k per tile = 1024 16B-chunks; thread t owns chunks
  // {t, t+256, t+512, t+768} = rows rA+64i, slot t&3, global chunk sg.
  const int sg = (t & 3) ^ ((t >> 3) & 3);
  const int rA = t >> 2;
  const float* pA[4];
#pragma unroll
  for (int i = 0; i < 4; ++i)
    pA[i] = In + (size_t)(r0 + rA + 64 * i) * 1000 + sg * 8;
  // B: 128 rows x 32 k = 512 chunks; thread t owns {t, t+256}; pre-swizzled
  // global source, linear LDS dest (gl_lds writes wave-base + lane*16).
  size_t b_src[2]; int bdst[2];
#pragma unroll
  for (int i = 0; i < 2; ++i) {
    b_src[i] = (size_t)(c0 + rA + 64 * i) * 1024 + sg * 8;
    bdst[i] = (t + 256 * i) * 8;
  }
  // fragment LDS element offsets (within one buffer)
  int a_eoff[8], b_eoff[4];
#pragma unroll
  for (int i = 0; i < 8; ++i) {
    int ar = wr * 128 + i * 16 + c16;
    a_eoff[i] = ar * 32 + ((g16 ^ ((ar >> 1) & 3)) << 3);
  }
#pragma unroll
  for (int i = 0; i < 4; ++i) {
    int br = wc * 64 + i * 16 + c16;
    b_eoff[i] = br * 32 + ((g16 ^ ((br >> 1) & 3)) << 3);
  }

  f32x4 acc[8][4];
#pragma unroll
  for (int mi = 0; mi < 8; ++mi)
#pragma unroll
    for (int ni = 0; ni < 4; ++ni) acc[mi][ni] = (f32x4)(0.f);

  float4 La[8];  // single A staging reg set (32 VGPR)

#define LOADA(js)                                                              \
  {                                                                            \
    if ((js) < 31 || sg == 0) {                                                \
      _Pragma("unroll") for (int i = 0; i < 4; ++i) {                          \
        const float4* q = (const float4*)(pA[i] + (size_t)(js) * 32);          \
        La[2 * i] = q[0]; La[2 * i + 1] = q[1];                                \
      }                                                                        \
    } else {                                                                   \
      _Pragma("unroll") for (int i = 0; i < 8; ++i)                            \
        La[i] = make_float4(0.f, 0.f, 0.f, 0.f);                               \
    }                                                                          \
  }

#define CVWRA(dst)                                                             \
  {                                                                            \
    _Pragma("unroll") for (int i = 0; i < 4; ++i) {                            \
      union { unsigned short u[8]; uint4 v; } pk;                              \
      pk.u[0] = f2bf(2.f * La[2 * i].x); pk.u[1] = f2bf(2.f * La[2 * i].y);    \
      pk.u[2] = f2bf(2.f * La[2 * i].z); pk.u[3] = f2bf(2.f * La[2 * i].w);    \
      pk.u[4] = f2bf(2.f * La[2 * i + 1].x); pk.u[5] = f2bf(2.f * La[2 * i + 1].y); \
      pk.u[6] = f2bf(2.f * La[2 * i + 1].z); pk.u[7] = f2bf(2.f * La[2 * i + 1].w); \
      *(uint4*)((dst) + t * 8 + i * 2048) = pk.v;                              \
    }                                                                          \
  }

#define COMPUTE(pa, pb)                                                        \
  {                                                                            \
    bf16x8 af[4], af2[4], bv[4];                                               \
    _Pragma("unroll") for (int i = 0; i < 4; ++i)                              \
        af[i] = *(const bf16x8*)((pa) + a_eoff[i]);                            \
    _Pragma("unroll") for (int i = 0; i < 4; ++i)                              \
        bv[i] = *(const bf16x8*)((pb) + b_eoff[i]);                            \
    _Pragma("unroll") for (int i = 0; i < 4; ++i)                              \
        af2[i] = *(const bf16x8*)((pa) + a_eoff[i + 4]);                       \
    _Pragma("unroll") for (int mi = 0; mi < 4; ++mi)                           \
      _Pragma("unroll") for (int ni = 0; ni < 4; ++ni)                         \
        acc[mi][ni] =                                                          \
            __builtin_amdgcn_mfma_f32_16x16x32_bf16(af[mi], bv[ni], acc[mi][ni], 0, 0, 0); \
    _Pragma("unroll") for (int mi = 0; mi < 4; ++mi)                           \
      _Pragma("unroll") for (int ni = 0; ni < 4; ++ni)                         \
        acc[mi + 4][ni] =                                                      \
            __builtin_amdgcn_mfma_f32_16x16x32_bf16(af2[mi], bv[ni], acc[mi + 4][ni], 0, 0, 0); \
  }

  unsigned short* a_rd = lds;
  unsigned short* a_wr = lds + 8192;
  unsigned short* b_rd = lds + 16384;
  unsigned short* b_nx = lds + 16384 + 4096;
  unsigned short* b_st = lds + 16384 + 8192;

  // ---- prologue ----
  LOADA(0);
  gl2lds16(Bg + b_src[0], b_rd + bdst[0]);
  gl2lds16(Bg + b_src[1], b_rd + bdst[1]);
  CVWRA(a_rd);  // compiler waits A(0) (vmcnt<=2); B(0) stays in flight
  LOADA(1);
  gl2lds16(Bg + b_src[0] + 32, b_nx + bdst[0]);
  gl2lds16(Bg + b_src[1] + 32, b_nx + bdst[1]);
  __builtin_amdgcn_sched_barrier(0);
  __builtin_amdgcn_s_waitcnt(0x07A);  // vmcnt(10) lgkm(0): B(0)+ds_writes done
  __builtin_amdgcn_s_barrier();
  __builtin_amdgcn_sched_barrier(0);

  // ---- main loop: region J computes tile J ----
  for (int J = 0; J < 30; ++J) {
    COMPUTE(a_rd, b_rd);
    CVWRA(a_wr);   // A(J+1)->LDS; implicit vmcnt<=2 leaves B(J+1) in flight
    LOADA(J + 2);
    gl2lds16(Bg + b_src[0] + (size_t)(J + 2) * 32, b_st + bdst[0]);
    gl2lds16(Bg + b_src[1] + (size_t)(J + 2) * 32, b_st + bdst[1]);
    __builtin_amdgcn_sched_barrier(0);
    __builtin_amdgcn_s_waitcnt(0x07A);  // vmcnt(10) lgkm(0): B(J+1) landed
    __builtin_amdgcn_s_barrier();
    __builtin_amdgcn_sched_barrier(0);
    unsigned short* x = a_rd; a_rd = a_wr; a_wr = x;
    x = b_rd; b_rd = b_nx; b_nx = b_st; b_st = x;
  }
  // region 30: no more staging to issue
  COMPUTE(a_rd, b_rd);
  CVWRA(a_wr);  // A(31)
  __builtin_amdgcn_sched_barrier(0);
  __builtin_amdgcn_s_waitcnt(0x070);  // vmcnt(0) lgkm(0): B(31) landed
  __builtin_amdgcn_s_barrier();
  __builtin_amdgcn_sched_barrier(0);
  {
    unsigned short* x = a_rd; a_rd = a_wr; a_wr = x;
    x = b_rd; b_rd = b_nx; b_nx = b_st; b_st = x;
  }
  COMPUTE(a_rd, b_rd);  // tile 31
  __syncthreads();      // drain before aliasing LDS for epilogue

  // ---- epilogue (zbuf aliases the staging LDS) ----
  float* zbuf = (float*)lds;   // [4 waves][128 rows]
  float* lbuf = zbuf + 512;    // [4]
  float rs[4]; int gcol[4];
#pragma unroll
  for (int ni = 0; ni < 4; ++ni) {
    gcol[ni] = c0 + wc * 64 + ni * 16 + c16;
    rs[ni]   = rowsum[gcol[ni]];
  }
  float lacc = 0.f;  // 0.9*S_label + 1e-4*sum S
#pragma unroll
  for (int mi = 0; mi < 8; ++mi) {
#pragma unroll
    for (int r = 0; r < 4; ++r) {
      int lrow = mi * 16 + g16 * 4 + r;
      int labv = labels[r0 + wr * 128 + lrow];
      float e = 0.f;
#pragma unroll
      for (int ni = 0; ni < 4; ++ni) {
        float S = acc[mi][ni][r] - rs[ni];  // padded cols: S==0, harmless
        e += __expf(S - 40.f);
        lacc += 1e-4f * S;
        if (gcol[ni] == labv) lacc += 0.9f * S;
      }
      e += __shfl_xor(e, 1, 64);
      e += __shfl_xor(e, 2, 64);
      e += __shfl_xor(e, 4, 64);
      e += __shfl_xor(e, 8, 64);
      if (c16 == 0) zbuf[w * 128 + lrow] = e;
    }
  }
#pragma unroll
  for (int d = 1; d < 64; d <<= 1) lacc += __shfl_xor(lacc, d, 64);
  if (lane == 0) lbuf[w] = lacc;
  __syncthreads();
  {  // row t of the 256-row block: sum wc=0,1 wave halves
    int wrg = t >> 7, l7 = t & 127;
    float z = zbuf[(wrg * 2 + 0) * 128 + l7] + zbuf[(wrg * 2 + 1) * 128 + l7];
    Z[(size_t)ct * 16384 + r0 + t] = z;  // single writer per slot
  }
  if (t == 0) atomicAdd(lin, lbuf[0] + lbuf[1] + lbuf[2] + lbuf[3]);
#undef LOADA
#undef CVWRA
#undef COMPUTE
}

// out = mean_r(40 + log(sum_ct Z[ct][r])) - lin/16384
__global__ __launch_bounds__(256) void finalize_k(const float* __restrict__ Z,
                                                  const float* __restrict__ lin,
                                                  float* __restrict__ out) {
  int t = threadIdx.x;
  int row = blockIdx.x * 256 + t;
  float zs = 0.f;
#pragma unroll
  for (int q = 0; q < 8; ++q) zs += Z[(size_t)q * 16384 + row];
  float v = 40.f + logf(zs);
#pragma unroll
  for (int d = 1; d < 64; d <<= 1) v += __shfl_xor(v, d, 64);
  __shared__ float s[4];
  if ((t & 63) == 0) s[t >> 6] = v;
  __syncthreads();
  if (t == 0) {
    float tot = s[0] + s[1] + s[2] + s[3];
    if (blockIdx.x == 0) tot -= lin[0];
    atomicAdd(out, tot * (1.f / 16384.f));
  }
}

extern "C" void kernel_launch(void* const* d_in, const int* in_sizes, int n_in,
                              void* d_out, int out_size, void* d_ws, size_t ws_size,
                              hipStream_t stream) {
  const float* inputs = (const float*)d_in[0];
  const int* labraw   = (const int*)d_in[1];
  const float* code   = (const float*)d_in[2];

  unsigned short* b_bf = (unsigned short*)d_ws;                 // 2 MB
  float* rowsum        = (float*)(b_bf + (size_t)1024 * 1024);  // 4 KB
  float* Z             = rowsum + 1024;                         // [8][16384] = 512 KB
  float* lin           = Z + 8 * 16384;                         // 4 B
  int* labs            = (int*)(lin + 1);                       // 64 KB

  // 3 graph nodes; A-cast fused into GEMM, prep is 1088 blocks (~6 MB traffic)
  prep_bl_k<<<1088, 256, 0, stream>>>(code, labraw, b_bf, rowsum, labs, lin,
                                      (float*)d_out);
  coding_loss_k<<<512, 256, 0, stream>>>(inputs, b_bf, rowsum, labs, Z, lin);
  finalize_k<<<64, 256, 0, stream>>>(Z, lin, (float*)d_out);
}